// Round 3
// baseline (432.357 us; speedup 1.0000x reference)
//
#include <hip/hip_runtime.h>
#include <hip/hip_bf16.h>

// DIAGNOSTIC round: pure fp32 VALU implementation mirroring the reference
// exactly. No MFMA, no bf16, no tiled pair tables, no symmetrization trick.
// Purpose: bisect the deterministic 2.2e-2 error seen in rounds 1-2 (it was
// invariant under a 512x MFMA-precision change => logic/shared-path bug).
// One block per batch row; 256 threads.

#define NF 40
#define ED 64
#define AS 32
#define NPAIR 780

__global__ __launch_bounds__(256) void afm_fp32_kernel(
    const float* __restrict__ x, const float* __restrict__ attn_w,
    const float* __restrict__ attn_b, const float* __restrict__ proj_w,
    const float* __restrict__ proj_b, const float* __restrict__ fc_w,
    const float* __restrict__ fc_b, float* __restrict__ out) {
  __shared__ float xs[NF * ED];        // 10240 B, stride 64: P4 reads are 2-way (free)
  __shared__ float logits[NPAIR];      // 3120 B
  __shared__ float red_max[4], red_sum[4];
  __shared__ float attnp[4][ED];       // 1024 B partials

  const int tid = threadIdx.x;
  const int lane = tid & 63;
  const int wid = tid >> 6;
  const int b = blockIdx.x;
  const float* xg = x + b * (NF * ED);

  // ---- stage x[b] into LDS (coalesced float4)
  for (int v = tid; v < NF * ED / 4; v += 256)
    ((float4*)xs)[v] = ((const float4*)xg)[v];
  __syncthreads();

  // ---- P2: logits per pair, reference triu order, pure fp32.
  // attn_w reads are thread-uniform (same (d,a) for every lane in lockstep)
  // -> scalarized/broadcast, L1-cached.
  for (int s = tid; s < NPAIR; s += 256) {
    int i = 0, rem = s;
    while (rem >= 39 - i) { rem -= 39 - i; ++i; }  // row i has 39-i pairs
    const int j = i + 1 + rem;
    float acc[AS];
#pragma unroll
    for (int a = 0; a < AS; ++a) acc[a] = 0.f;
    const float* xi = xs + i * ED;
    const float* xj = xs + j * ED;
    for (int d = 0; d < ED; ++d) {
      float ip = xi[d] * xj[d];
      const float4* wr = (const float4*)(attn_w + d * AS);
#pragma unroll
      for (int a4 = 0; a4 < AS / 4; ++a4) {
        float4 w4 = wr[a4];
        acc[a4 * 4 + 0] = fmaf(ip, w4.x, acc[a4 * 4 + 0]);
        acc[a4 * 4 + 1] = fmaf(ip, w4.y, acc[a4 * 4 + 1]);
        acc[a4 * 4 + 2] = fmaf(ip, w4.z, acc[a4 * 4 + 2]);
        acc[a4 * 4 + 3] = fmaf(ip, w4.w, acc[a4 * 4 + 3]);
      }
    }
    float lg = 0.f;
#pragma unroll
    for (int a = 0; a < AS; ++a)
      lg += fmaxf(acc[a] + attn_b[a], 0.f) * proj_w[a];
    logits[s] = lg;  // proj_b dropped: softmax shift-invariant
  }
  __syncthreads();

  // ---- P3: softmax over the 780 pairs (precise expf; unnormalized e kept).
  float lm = -1e30f;
  for (int s = tid; s < NPAIR; s += 256) lm = fmaxf(lm, logits[s]);
#pragma unroll
  for (int off = 32; off >= 1; off >>= 1) lm = fmaxf(lm, __shfl_xor(lm, off));
  if (lane == 0) red_max[wid] = lm;
  __syncthreads();
  const float mall = fmaxf(fmaxf(red_max[0], red_max[1]),
                           fmaxf(red_max[2], red_max[3]));
  float lsum = 0.f;
  for (int s = tid; s < NPAIR; s += 256) {
    float e = expf(logits[s] - mall);
    logits[s] = e;
    lsum += e;
  }
#pragma unroll
  for (int off = 32; off >= 1; off >>= 1) lsum += __shfl_xor(lsum, off);
  if (lane == 0) red_sum[wid] = lsum;
  __syncthreads();
  const float total = red_sum[0] + red_sum[1] + red_sum[2] + red_sum[3];

  // ---- P4: attn[d] = sum_s e_s * x_i[d] * x_j[d], direct (4 groups over s).
  {
    const int d = tid & 63;
    const int g = tid >> 6;  // == wid; s-decode below is wave-uniform (scalar)
    float pa = 0.f;
    for (int s = g; s < NPAIR; s += 4) {
      int i = 0, rem = s;
      while (rem >= 39 - i) { rem -= 39 - i; ++i; }
      const int j = i + 1 + rem;
      pa = fmaf(logits[s] * xs[i * ED + d], xs[j * ED + d], pa);
    }
    attnp[g][d] = pa;
  }
  __syncthreads();

  // ---- P5: y = (attn / total) . fc_w + fc_b, wave 0 only.
  if (tid < 64) {
    const int d = tid;
    float v = (attnp[0][d] + attnp[1][d] + attnp[2][d] + attnp[3][d]) * fc_w[d];
#pragma unroll
    for (int off = 1; off <= 32; off <<= 1) v += __shfl_xor(v, off);
    if (tid == 0) out[b] = v / total + fc_b[0];
  }
  (void)proj_b;
}

extern "C" void kernel_launch(void* const* d_in, const int* in_sizes, int n_in,
                              void* d_out, int out_size, void* d_ws, size_t ws_size,
                              hipStream_t stream) {
  (void)in_sizes; (void)n_in; (void)out_size; (void)d_ws; (void)ws_size;
  afm_fp32_kernel<<<2048, 256, 0, stream>>>(
      (const float*)d_in[0], (const float*)d_in[1], (const float*)d_in[2],
      (const float*)d_in[3], (const float*)d_in[4], (const float*)d_in[5],
      (const float*)d_in[6], (float*)d_out);
}

// Round 5
// 146.296 us; speedup vs baseline: 2.9554x; 2.9554x over previous
//
#include <hip/hip_runtime.h>
#include <hip/hip_bf16.h>

// Round 5: r4 structure + THE FIX. r1/r2/r4's deterministic error was the
// diagonal-block pair decode emitting (1,1) and omitting (1,3) (10 spurious +
// 10 missing pairs of 780). P2 = split-bf16 MFMA; P3/P4/P5 = validated scalar.

#define NF 40
#define ED 64
#define AS 32
#define NPAIR 780
#define NSLOT 784
#define NTILE 49
#define XS_STRIDE 68   // floats; 272B rows, 16B-aligned; P2/P4 reads <=4-way

typedef __attribute__((ext_vector_type(4))) float f32x4;
typedef __attribute__((ext_vector_type(8))) short bf16x8;

union ABFrag { bf16x8 v; unsigned int u[4]; uint4 q; };

__device__ __forceinline__ unsigned short bfbits(float f) {
  union { __hip_bfloat16 h; unsigned short s; } c;
  c.h = __float2bfloat16(f);  // RNE
  return c.s;
}
__device__ __forceinline__ float bf2f(unsigned short s) {
  union { float f; unsigned int u; } c;
  c.u = ((unsigned int)s) << 16;
  return c.f;
}
// hi = bf16(a),bf16(b); lo = bf16(a-hi_a),bf16(b-hi_b): ~17-bit split
__device__ __forceinline__ void split_pack(float a, float b,
                                           unsigned int& hi, unsigned int& lo) {
  unsigned short ah = bfbits(a), bh = bfbits(b);
  hi = (unsigned int)ah | ((unsigned int)bh << 16);
  lo = (unsigned int)bfbits(a - bf2f(ah)) | ((unsigned int)bfbits(b - bf2f(bh)) << 16);
}

__global__ __launch_bounds__(256) void afm_kernel(
    const float* __restrict__ x, const float* __restrict__ attn_w,
    const float* __restrict__ attn_b, const float* __restrict__ proj_w,
    const float* __restrict__ proj_b, const float* __restrict__ fc_w,
    const float* __restrict__ fc_b, float* __restrict__ out) {
  __shared__ __align__(16) float xs[NF * XS_STRIDE];  // 10880 B fp32 x (padded)
  __shared__ __align__(16) float logits[NSLOT];       // 3136 B
  __shared__ float red_max[4], red_sum[4];
  __shared__ float attnp[4][ED];                      // 1024 B partials
  __shared__ unsigned char pi_t[NSLOT], pj_t[NSLOT];

  const int tid = threadIdx.x;
  const int lane = tid & 63;
  const int wid = tid >> 6;
  const int quad = lane >> 4;
  const int col = lane & 15;
  const int b = blockIdx.x;
  const float* xg = x + b * (NF * ED);

  // ---- P1a: pair tables. Slots: t<45 off-diag 4x4 field-blocks (bi<bj),
  // 16 pairs each; 720..779 the 10 diagonal blocks' 6 in-block pairs;
  // 780..783 padding.
  for (int s = tid; s < NSLOT; s += 256) {
    int i = 0, j = 0;
    if (s < 720) {
      int t = s >> 4, m = s & 15;
      int bi = 0, tt = t;
      while (tt >= 9 - bi) { tt -= 9 - bi; ++bi; }
      int bj = bi + 1 + tt;
      i = bi * 4 + (m >> 2);
      j = bj * 4 + (m & 3);
    } else if (s < NPAIR) {
      int idx = s - 720;
      int db = idx / 6;
      int r = idx - db * 6;
      // in-block pairs (0,1),(0,2),(0,3),(1,2),(1,3),(2,3)  [FIXED: was r-2]
      int a = r < 3 ? 0 : (r < 5 ? 1 : 2);
      int bb = r < 3 ? r + 1 : (r < 5 ? r - 1 : 3);
      i = db * 4 + a;
      j = db * 4 + bb;
    }
    pi_t[s] = (unsigned char)i;
    pj_t[s] = (unsigned char)j;
  }

  // ---- P1b: stage x (fp32 padded); per-lane constants; attn_w B-fragments
  // (hi+lo) into registers.
  for (int v = tid; v < NF * 16; v += 256) {  // 40 rows x 16 float4
    int f = v >> 4, c4 = v & 15;
    *(float4*)(xs + f * XS_STRIDE + c4 * 4) = *(const float4*)(xg + f * ED + c4 * 4);
  }
  const float ab0 = attn_b[col], ab1 = attn_b[col + 16];
  const float pw0 = proj_w[col], pw1 = proj_w[col + 16];

  ABFrag fbh[2][2], fbl[2][2];  // [k-step][n-tile]: B[k][n] = attn_w[k][n]
#pragma unroll
  for (int kk = 0; kk < 2; ++kk)
#pragma unroll
    for (int nt = 0; nt < 2; ++nt)
#pragma unroll
      for (int jp = 0; jp < 4; ++jp) {
        int k = kk * 32 + quad * 8 + jp * 2;
        int n = nt * 16 + col;
        split_pack(attn_w[k * AS + n], attn_w[(k + 1) * AS + n],
                   fbh[kk][nt].u[jp], fbl[kk][nt].u[jp]);
      }
  __syncthreads();

  // ---- P2: logits via split-bf16 MFMA. Wave handles tiles wid, wid+4, ...
  // A-frag: A[m=col][k=quad*8+j]; pair s = t*16 + m.
  for (int t = wid; t < NTILE; t += 4) {
    int s = t * 16 + col;
    int fi = pi_t[s], fj = pj_t[s];
    const float* xi = xs + fi * XS_STRIDE;
    const float* xj = xs + fj * XS_STRIDE;
    ABFrag fah[2], fal[2];
#pragma unroll
    for (int kk = 0; kk < 2; ++kk) {
      int kb = kk * 32 + quad * 8;
      float4 i0 = *(const float4*)(xi + kb);
      float4 i1 = *(const float4*)(xi + kb + 4);
      float4 j0 = *(const float4*)(xj + kb);
      float4 j1 = *(const float4*)(xj + kb + 4);
      split_pack(i0.x * j0.x, i0.y * j0.y, fah[kk].u[0], fal[kk].u[0]);
      split_pack(i0.z * j0.z, i0.w * j0.w, fah[kk].u[1], fal[kk].u[1]);
      split_pack(i1.x * j1.x, i1.y * j1.y, fah[kk].u[2], fal[kk].u[2]);
      split_pack(i1.z * j1.z, i1.w * j1.w, fah[kk].u[3], fal[kk].u[3]);
    }
    f32x4 acc0 = {0.f, 0.f, 0.f, 0.f}, acc1 = {0.f, 0.f, 0.f, 0.f};
    // hi*hi + hi*lo + lo*hi (drop lo*lo ~ 2^-18)
    acc0 = __builtin_amdgcn_mfma_f32_16x16x32_bf16(fah[0].v, fbh[0][0].v, acc0, 0, 0, 0);
    acc0 = __builtin_amdgcn_mfma_f32_16x16x32_bf16(fah[1].v, fbh[1][0].v, acc0, 0, 0, 0);
    acc0 = __builtin_amdgcn_mfma_f32_16x16x32_bf16(fah[0].v, fbl[0][0].v, acc0, 0, 0, 0);
    acc0 = __builtin_amdgcn_mfma_f32_16x16x32_bf16(fah[1].v, fbl[1][0].v, acc0, 0, 0, 0);
    acc0 = __builtin_amdgcn_mfma_f32_16x16x32_bf16(fal[0].v, fbh[0][0].v, acc0, 0, 0, 0);
    acc0 = __builtin_amdgcn_mfma_f32_16x16x32_bf16(fal[1].v, fbh[1][0].v, acc0, 0, 0, 0);
    acc1 = __builtin_amdgcn_mfma_f32_16x16x32_bf16(fah[0].v, fbh[0][1].v, acc1, 0, 0, 0);
    acc1 = __builtin_amdgcn_mfma_f32_16x16x32_bf16(fah[1].v, fbh[1][1].v, acc1, 0, 0, 0);
    acc1 = __builtin_amdgcn_mfma_f32_16x16x32_bf16(fah[0].v, fbl[0][1].v, acc1, 0, 0, 0);
    acc1 = __builtin_amdgcn_mfma_f32_16x16x32_bf16(fah[1].v, fbl[1][1].v, acc1, 0, 0, 0);
    acc1 = __builtin_amdgcn_mfma_f32_16x16x32_bf16(fal[0].v, fbh[0][1].v, acc1, 0, 0, 0);
    acc1 = __builtin_amdgcn_mfma_f32_16x16x32_bf16(fal[1].v, fbh[1][1].v, acc1, 0, 0, 0);
    // Fused relu+proj; C/D: lane holds D[row=quad*4+r][col] (m89-verified).
    float c0 = fmaxf(acc0[0] + ab0, 0.f) * pw0 + fmaxf(acc1[0] + ab1, 0.f) * pw1;
    float c1 = fmaxf(acc0[1] + ab0, 0.f) * pw0 + fmaxf(acc1[1] + ab1, 0.f) * pw1;
    float c2 = fmaxf(acc0[2] + ab0, 0.f) * pw0 + fmaxf(acc1[2] + ab1, 0.f) * pw1;
    float c3 = fmaxf(acc0[3] + ab0, 0.f) * pw0 + fmaxf(acc1[3] + ab1, 0.f) * pw1;
#pragma unroll
    for (int off = 1; off <= 8; off <<= 1) {
      c0 += __shfl_xor(c0, off);
      c1 += __shfl_xor(c1, off);
      c2 += __shfl_xor(c2, off);
      c3 += __shfl_xor(c3, off);
    }
    if (col == 0) {
      int base = t * 16 + quad * 4;
      float4 st;
      st.x = (base + 0 < NPAIR) ? c0 : -1e30f;
      st.y = (base + 1 < NPAIR) ? c1 : -1e30f;
      st.z = (base + 2 < NPAIR) ? c2 : -1e30f;
      st.w = (base + 3 < NPAIR) ? c3 : -1e30f;
      *(float4*)(logits + base) = st;
    }
  }
  __syncthreads();

  // ---- P3: softmax over 784 slots (pads = -1e30 -> e=0). [validated]
  float lm = -1e30f;
  for (int s2 = tid; s2 < NSLOT; s2 += 256) lm = fmaxf(lm, logits[s2]);
#pragma unroll
  for (int off = 32; off >= 1; off >>= 1) lm = fmaxf(lm, __shfl_xor(lm, off));
  if (lane == 0) red_max[wid] = lm;
  __syncthreads();
  const float mall = fmaxf(fmaxf(red_max[0], red_max[1]),
                           fmaxf(red_max[2], red_max[3]));
  float lsum = 0.f;
  for (int s2 = tid; s2 < NSLOT; s2 += 256) {
    float e = expf(logits[s2] - mall);
    logits[s2] = e;  // unnormalized; divide once at the end
    lsum += e;
  }
#pragma unroll
  for (int off = 32; off >= 1; off >>= 1) lsum += __shfl_xor(lsum, off);
  if (lane == 0) red_sum[wid] = lsum;
  __syncthreads();
  const float total = red_sum[0] + red_sum[1] + red_sum[2] + red_sum[3];

  // ---- P4: attn[d] = sum_s e_s x_i[d] x_j[d], scalar direct. [validated]
  {
    const int d = tid & 63;
    const int g = tid >> 6;
    float pa = 0.f;
    for (int s = g; s < NPAIR; s += 4) {
      const int i = pi_t[s], j = pj_t[s];
      pa = fmaf(logits[s] * xs[i * XS_STRIDE + d], xs[j * XS_STRIDE + d], pa);
    }
    attnp[g][d] = pa;
  }
  __syncthreads();

  // ---- P5: y = (attn / total) . fc_w + fc_b, wave 0 only. [validated]
  if (tid < 64) {
    const int d = tid;
    float v = (attnp[0][d] + attnp[1][d] + attnp[2][d] + attnp[3][d]) * fc_w[d];
#pragma unroll
    for (int off = 1; off <= 32; off <<= 1) v += __shfl_xor(v, off);
    if (tid == 0) out[b] = v / total + fc_b[0];
  }
  (void)proj_b;  // cancels in softmax
}

extern "C" void kernel_launch(void* const* d_in, const int* in_sizes, int n_in,
                              void* d_out, int out_size, void* d_ws, size_t ws_size,
                              hipStream_t stream) {
  (void)in_sizes; (void)n_in; (void)out_size; (void)d_ws; (void)ws_size;
  afm_kernel<<<2048, 256, 0, stream>>>(
      (const float*)d_in[0], (const float*)d_in[1], (const float*)d_in[2],
      (const float*)d_in[3], (const float*)d_in[4], (const float*)d_in[5],
      (const float*)d_in[6], (float*)d_out);
}

// Round 7
// 120.605 us; speedup vs baseline: 3.5849x; 1.2130x over previous
//
#include <hip/hip_runtime.h>
#include <hip/hip_bf16.h>

// Round 7: r6 + determinism fix. r6's post-timing divergence (2.4e-4 fresh vs
// 6e-2 after graph replays) = uninitialized LDS: Smh/Sml rows 40-47 are read
// as A-fragments but were never written. Full zero-fill restores determinism.
// P2 = split-bf16 MFMA logits (r5-validated). P4 = MFMA symmetrization.

#define NF 40
#define ED 64
#define AS 32
#define NPAIR 780
#define NSLOT 784
#define NTILE 49
#define XS_STRIDE 68   // floats; 272B rows, 16B-aligned
#define SM_STRIDE 72   // shorts; 144B rows, 16B-aligned

typedef __attribute__((ext_vector_type(4))) float f32x4;
typedef __attribute__((ext_vector_type(8))) short bf16x8;

union ABFrag { bf16x8 v; unsigned int u[4]; uint4 q; };

__device__ __forceinline__ unsigned short bfbits(float f) {
  union { __hip_bfloat16 h; unsigned short s; } c;
  c.h = __float2bfloat16(f);  // RNE
  return c.s;
}
__device__ __forceinline__ float bf2f(unsigned short s) {
  union { float f; unsigned int u; } c;
  c.u = ((unsigned int)s) << 16;
  return c.f;
}
// hi = bf16(a),bf16(b); lo = bf16(a-hi_a),bf16(b-hi_b): ~17-bit split
__device__ __forceinline__ void split_pack(float a, float b,
                                           unsigned int& hi, unsigned int& lo) {
  unsigned short ah = bfbits(a), bh = bfbits(b);
  hi = (unsigned int)ah | ((unsigned int)bh << 16);
  lo = (unsigned int)bfbits(a - bf2f(ah)) | ((unsigned int)bfbits(b - bf2f(bh)) << 16);
}

__global__ __launch_bounds__(256) void afm_kernel(
    const float* __restrict__ x, const float* __restrict__ attn_w,
    const float* __restrict__ attn_b, const float* __restrict__ proj_w,
    const float* __restrict__ proj_b, const float* __restrict__ fc_w,
    const float* __restrict__ fc_b, float* __restrict__ out) {
  __shared__ __align__(16) float xs[NF * XS_STRIDE];            // 10880 B
  __shared__ __align__(16) float logits[NSLOT];                 // 3136 B
  __shared__ __align__(16) unsigned short Smh[48 * SM_STRIDE];  // 6912 B
  __shared__ __align__(16) unsigned short Sml[48 * SM_STRIDE];  // 6912 B
  __shared__ float red_max[4], red_sum[4], wsum[4];
  __shared__ unsigned char pi_t[NSLOT], pj_t[NSLOT];

  const int tid = threadIdx.x;
  const int lane = tid & 63;
  const int wid = tid >> 6;
  const int quad = lane >> 4;
  const int col = lane & 15;
  const int b = blockIdx.x;
  const float* xg = x + b * (NF * ED);

  // ---- P1a: FULL zero of Smh/Sml (every element later read must be defined:
  // scatter covers off-diag i,j<40; everything else must be exact 0.0) +
  // pair tables (r5-fixed decode).
  for (int v = tid; v < (48 * SM_STRIDE) / 2; v += 256) {
    ((unsigned int*)Smh)[v] = 0u;
    ((unsigned int*)Sml)[v] = 0u;
  }
  for (int s = tid; s < NSLOT; s += 256) {
    int i = 0, j = 0;
    if (s < 720) {
      int t = s >> 4, m = s & 15;
      int bi = 0, tt = t;
      while (tt >= 9 - bi) { tt -= 9 - bi; ++bi; }
      int bj = bi + 1 + tt;
      i = bi * 4 + (m >> 2);
      j = bj * 4 + (m & 3);
    } else if (s < NPAIR) {
      int idx = s - 720;
      int db = idx / 6;
      int r = idx - db * 6;
      // in-block pairs (0,1),(0,2),(0,3),(1,2),(1,3),(2,3)
      int a = r < 3 ? 0 : (r < 5 ? 1 : 2);
      int bb = r < 3 ? r + 1 : (r < 5 ? r - 1 : 3);
      i = db * 4 + a;
      j = db * 4 + bb;
    }
    pi_t[s] = (unsigned char)i;
    pj_t[s] = (unsigned char)j;
  }

  // ---- P1b: stage x (fp32 padded); per-lane constants; attn_w B-fragments.
  for (int v = tid; v < NF * 16; v += 256) {  // 40 rows x 16 float4
    int f = v >> 4, c4 = v & 15;
    *(float4*)(xs + f * XS_STRIDE + c4 * 4) = *(const float4*)(xg + f * ED + c4 * 4);
  }
  const float ab0 = attn_b[col], ab1 = attn_b[col + 16];
  const float pw0 = proj_w[col], pw1 = proj_w[col + 16];
  const float fcw = fc_w[wid * 16 + col];
  const float fcb = fc_b[0];

  ABFrag fbh[2][2], fbl[2][2];  // [k-step][n-tile]: B[k][n] = attn_w[k][n]
#pragma unroll
  for (int kk = 0; kk < 2; ++kk)
#pragma unroll
    for (int nt = 0; nt < 2; ++nt)
#pragma unroll
      for (int jp = 0; jp < 4; ++jp) {
        int k = kk * 32 + quad * 8 + jp * 2;
        int n = nt * 16 + col;
        split_pack(attn_w[k * AS + n], attn_w[(k + 1) * AS + n],
                   fbh[kk][nt].u[jp], fbl[kk][nt].u[jp]);
      }
  __syncthreads();

  // ---- P2: logits via split-bf16 MFMA (r5-validated verbatim).
  for (int t = wid; t < NTILE; t += 4) {
    int s = t * 16 + col;
    int fi = pi_t[s], fj = pj_t[s];
    const float* xi = xs + fi * XS_STRIDE;
    const float* xj = xs + fj * XS_STRIDE;
    ABFrag fah[2], fal[2];
#pragma unroll
    for (int kk = 0; kk < 2; ++kk) {
      int kb = kk * 32 + quad * 8;
      float4 i0 = *(const float4*)(xi + kb);
      float4 i1 = *(const float4*)(xi + kb + 4);
      float4 j0 = *(const float4*)(xj + kb);
      float4 j1 = *(const float4*)(xj + kb + 4);
      split_pack(i0.x * j0.x, i0.y * j0.y, fah[kk].u[0], fal[kk].u[0]);
      split_pack(i0.z * j0.z, i0.w * j0.w, fah[kk].u[1], fal[kk].u[1]);
      split_pack(i1.x * j1.x, i1.y * j1.y, fah[kk].u[2], fal[kk].u[2]);
      split_pack(i1.z * j1.z, i1.w * j1.w, fah[kk].u[3], fal[kk].u[3]);
    }
    f32x4 acc0 = {0.f, 0.f, 0.f, 0.f}, acc1 = {0.f, 0.f, 0.f, 0.f};
    acc0 = __builtin_amdgcn_mfma_f32_16x16x32_bf16(fah[0].v, fbh[0][0].v, acc0, 0, 0, 0);
    acc0 = __builtin_amdgcn_mfma_f32_16x16x32_bf16(fah[1].v, fbh[1][0].v, acc0, 0, 0, 0);
    acc0 = __builtin_amdgcn_mfma_f32_16x16x32_bf16(fah[0].v, fbl[0][0].v, acc0, 0, 0, 0);
    acc0 = __builtin_amdgcn_mfma_f32_16x16x32_bf16(fah[1].v, fbl[1][0].v, acc0, 0, 0, 0);
    acc0 = __builtin_amdgcn_mfma_f32_16x16x32_bf16(fal[0].v, fbh[0][0].v, acc0, 0, 0, 0);
    acc0 = __builtin_amdgcn_mfma_f32_16x16x32_bf16(fal[1].v, fbh[1][0].v, acc0, 0, 0, 0);
    acc1 = __builtin_amdgcn_mfma_f32_16x16x32_bf16(fah[0].v, fbh[0][1].v, acc1, 0, 0, 0);
    acc1 = __builtin_amdgcn_mfma_f32_16x16x32_bf16(fah[1].v, fbh[1][1].v, acc1, 0, 0, 0);
    acc1 = __builtin_amdgcn_mfma_f32_16x16x32_bf16(fah[0].v, fbl[0][1].v, acc1, 0, 0, 0);
    acc1 = __builtin_amdgcn_mfma_f32_16x16x32_bf16(fah[1].v, fbl[1][1].v, acc1, 0, 0, 0);
    acc1 = __builtin_amdgcn_mfma_f32_16x16x32_bf16(fal[0].v, fbh[0][1].v, acc1, 0, 0, 0);
    acc1 = __builtin_amdgcn_mfma_f32_16x16x32_bf16(fal[1].v, fbh[1][1].v, acc1, 0, 0, 0);
    float c0 = fmaxf(acc0[0] + ab0, 0.f) * pw0 + fmaxf(acc1[0] + ab1, 0.f) * pw1;
    float c1 = fmaxf(acc0[1] + ab0, 0.f) * pw0 + fmaxf(acc1[1] + ab1, 0.f) * pw1;
    float c2 = fmaxf(acc0[2] + ab0, 0.f) * pw0 + fmaxf(acc1[2] + ab1, 0.f) * pw1;
    float c3 = fmaxf(acc0[3] + ab0, 0.f) * pw0 + fmaxf(acc1[3] + ab1, 0.f) * pw1;
#pragma unroll
    for (int off = 1; off <= 8; off <<= 1) {
      c0 += __shfl_xor(c0, off);
      c1 += __shfl_xor(c1, off);
      c2 += __shfl_xor(c2, off);
      c3 += __shfl_xor(c3, off);
    }
    if (col == 0) {
      int base = t * 16 + quad * 4;
      float4 st;
      st.x = (base + 0 < NPAIR) ? c0 : -1e30f;
      st.y = (base + 1 < NPAIR) ? c1 : -1e30f;
      st.z = (base + 2 < NPAIR) ? c2 : -1e30f;
      st.w = (base + 3 < NPAIR) ? c3 : -1e30f;
      *(float4*)(logits + base) = st;
    }
  }
  __syncthreads();

  // ---- P3: softmax max, then exp fused with split-bf16 scatter into S'.
  float lm = -1e30f;
  for (int s2 = tid; s2 < NSLOT; s2 += 256) lm = fmaxf(lm, logits[s2]);
#pragma unroll
  for (int off = 32; off >= 1; off >>= 1) lm = fmaxf(lm, __shfl_xor(lm, off));
  if (lane == 0) red_max[wid] = lm;
  __syncthreads();
  const float mall = fmaxf(fmaxf(red_max[0], red_max[1]),
                           fmaxf(red_max[2], red_max[3]));
  float lsum = 0.f;
  for (int s2 = tid; s2 < NSLOT; s2 += 256) {
    float e = expf(logits[s2] - mall);
    lsum += e;  // pads: exp(-1e30-mall) = 0
    if (s2 < NPAIR) {
      const int i = pi_t[s2], j = pj_t[s2];
      unsigned short eh = bfbits(e);
      unsigned short el = bfbits(e - bf2f(eh));
      Smh[i * SM_STRIDE + j] = eh;
      Smh[j * SM_STRIDE + i] = eh;
      Sml[i * SM_STRIDE + j] = el;
      Sml[j * SM_STRIDE + i] = el;
    }
  }
#pragma unroll
  for (int off = 32; off >= 1; off >>= 1) lsum += __shfl_xor(lsum, off);
  if (lane == 0) red_sum[wid] = lsum;
  __syncthreads();  // covers Sm scatter + red_sum
  const float total = red_sum[0] + red_sum[1] + red_sum[2] + red_sum[3];

  // ---- P4: M = S' @ X via split MFMA. Wave wid owns d-tile [wid*16, +16).
  // A[m=i][k=j] from Smh/Sml (rows 40-47 are zero); B[k=j][n=d] from fp32 xs.
  // k>=40 k-steps predicated to zero on BOTH sides.
  const int dcol = wid * 16 + col;
  ABFrag fxh[2], fxl[2], fsh[3][2], fsl[3][2];
#pragma unroll
  for (int kt = 0; kt < 2; ++kt) {
    const int kbase = kt * 32 + quad * 8;
    const bool valid = (kt == 0) | (quad == 0);  // k range < 40
    if (valid) {
#pragma unroll
      for (int p = 0; p < 4; ++p) {
        float v0 = xs[(kbase + 2 * p) * XS_STRIDE + dcol];
        float v1 = xs[(kbase + 2 * p + 1) * XS_STRIDE + dcol];
        split_pack(v0, v1, fxh[kt].u[p], fxl[kt].u[p]);
      }
#pragma unroll
      for (int it = 0; it < 3; ++it) {
        fsh[it][kt].q = *(const uint4*)(Smh + (it * 16 + col) * SM_STRIDE + kbase);
        fsl[it][kt].q = *(const uint4*)(Sml + (it * 16 + col) * SM_STRIDE + kbase);
      }
    } else {
      fxh[kt].q = make_uint4(0, 0, 0, 0);
      fxl[kt].q = make_uint4(0, 0, 0, 0);
#pragma unroll
      for (int it = 0; it < 3; ++it) {
        fsh[it][kt].q = make_uint4(0, 0, 0, 0);
        fsl[it][kt].q = make_uint4(0, 0, 0, 0);
      }
    }
  }
  f32x4 mac[3];
#pragma unroll
  for (int it = 0; it < 3; ++it) {
    f32x4 z = {0.f, 0.f, 0.f, 0.f};
    z = __builtin_amdgcn_mfma_f32_16x16x32_bf16(fsh[it][0].v, fxh[0].v, z, 0, 0, 0);
    z = __builtin_amdgcn_mfma_f32_16x16x32_bf16(fsh[it][1].v, fxh[1].v, z, 0, 0, 0);
    z = __builtin_amdgcn_mfma_f32_16x16x32_bf16(fsh[it][0].v, fxl[0].v, z, 0, 0, 0);
    z = __builtin_amdgcn_mfma_f32_16x16x32_bf16(fsh[it][1].v, fxl[1].v, z, 0, 0, 0);
    z = __builtin_amdgcn_mfma_f32_16x16x32_bf16(fsl[it][0].v, fxh[0].v, z, 0, 0, 0);
    z = __builtin_amdgcn_mfma_f32_16x16x32_bf16(fsl[it][1].v, fxh[1].v, z, 0, 0, 0);
    mac[it] = z;
  }
  // attn_unnorm[d] = 0.5 * sum_i x_i[d] * M[i][d]; i rows 40-47 contribute 0
  // by construction and are not consumed.
  float part = 0.f;
#pragma unroll
  for (int r = 0; r < 4; ++r)
    part = fmaf(mac[0][r], xs[(quad * 4 + r) * XS_STRIDE + dcol], part);
#pragma unroll
  for (int r = 0; r < 4; ++r)
    part = fmaf(mac[1][r], xs[(16 + quad * 4 + r) * XS_STRIDE + dcol], part);
  if (quad < 2) {
#pragma unroll
    for (int r = 0; r < 4; ++r)
      part = fmaf(mac[2][r], xs[(32 + quad * 4 + r) * XS_STRIDE + dcol], part);
  }
  part += __shfl_xor(part, 16);  // reduce over quads (i groups)
  part += __shfl_xor(part, 32);
  float yp = part * fcw;         // fc_w[dcol]
#pragma unroll
  for (int off = 1; off <= 8; off <<= 1) yp += __shfl_xor(yp, off);  // over d
  if (lane == 0) wsum[wid] = yp;
  __syncthreads();
  if (tid == 0)
    out[b] = 0.5f * (wsum[0] + wsum[1] + wsum[2] + wsum[3]) / total + fcb;
  (void)proj_b;  // cancels in softmax
}

extern "C" void kernel_launch(void* const* d_in, const int* in_sizes, int n_in,
                              void* d_out, int out_size, void* d_ws, size_t ws_size,
                              hipStream_t stream) {
  (void)in_sizes; (void)n_in; (void)out_size; (void)d_ws; (void)ws_size;
  afm_kernel<<<2048, 256, 0, stream>>>(
      (const float*)d_in[0], (const float*)d_in[1], (const float*)d_in[2],
      (const float*)d_in[3], (const float*)d_in[4], (const float*)d_in[5],
      (const float*)d_in[6], (float*)d_out);
}

// Round 8
// 114.740 us; speedup vs baseline: 3.7682x; 1.0511x over previous
//
#include <hip/hip_runtime.h>
#include <hip/hip_bf16.h>

// Round 8: r7 minus two measured costs.
// (1) P2 drops the Al*Bh MFMA term: ip is plain-RNE bf16 (pack2, not
//     split_pack); w-quant still corrected via hoisted Ah*Bl. MFMA 12->8/tile,
//     per-tile convert VALU ~4x smaller.  (predicted +6e-5 error only)
// (2) P4 uses UPPER-TRIANGULAR S directly: sum_i x_i[d]*(S_up X)[i][d] =
//     sum_{i<j} e_ij x_i[d] x_j[d]. No symmetrized scatter (kills the 8-way
//     bank-conflict transposed writes), no 0.5 factor.

#define NF 40
#define ED 64
#define AS 32
#define NPAIR 780
#define NSLOT 784
#define NTILE 49
#define XS_STRIDE 68   // floats; 272B rows, 16B-aligned
#define SM_STRIDE 72   // shorts; 144B rows, 16B-aligned

typedef __attribute__((ext_vector_type(4))) float f32x4;
typedef __attribute__((ext_vector_type(8))) short bf16x8;

union ABFrag { bf16x8 v; unsigned int u[4]; uint4 q; };

__device__ __forceinline__ unsigned short bfbits(float f) {
  union { __hip_bfloat16 h; unsigned short s; } c;
  c.h = __float2bfloat16(f);  // RNE
  return c.s;
}
__device__ __forceinline__ float bf2f(unsigned short s) {
  union { float f; unsigned int u; } c;
  c.u = ((unsigned int)s) << 16;
  return c.f;
}
__device__ __forceinline__ unsigned int pack2(float a, float b) {
  return (unsigned int)bfbits(a) | ((unsigned int)bfbits(b) << 16);
}
// hi = bf16(a),bf16(b); lo = bf16(a-hi_a),bf16(b-hi_b): ~17-bit split
__device__ __forceinline__ void split_pack(float a, float b,
                                           unsigned int& hi, unsigned int& lo) {
  unsigned short ah = bfbits(a), bh = bfbits(b);
  hi = (unsigned int)ah | ((unsigned int)bh << 16);
  lo = (unsigned int)bfbits(a - bf2f(ah)) | ((unsigned int)bfbits(b - bf2f(bh)) << 16);
}

__global__ __launch_bounds__(256) void afm_kernel(
    const float* __restrict__ x, const float* __restrict__ attn_w,
    const float* __restrict__ attn_b, const float* __restrict__ proj_w,
    const float* __restrict__ proj_b, const float* __restrict__ fc_w,
    const float* __restrict__ fc_b, float* __restrict__ out) {
  __shared__ __align__(16) float xs[NF * XS_STRIDE];            // 10880 B
  __shared__ __align__(16) float logits[NSLOT];                 // 3136 B
  __shared__ __align__(16) unsigned short Smh[48 * SM_STRIDE];  // 6912 B
  __shared__ __align__(16) unsigned short Sml[48 * SM_STRIDE];  // 6912 B
  __shared__ float red_max[4], red_sum[4], wsum[4];
  __shared__ unsigned char pi_t[NSLOT], pj_t[NSLOT];

  const int tid = threadIdx.x;
  const int lane = tid & 63;
  const int wid = tid >> 6;
  const int quad = lane >> 4;
  const int col = lane & 15;
  const int b = blockIdx.x;
  const float* xg = x + b * (NF * ED);

  // ---- P1a: FULL zero of Smh/Sml (scatter only fills upper triangle; all
  // other read elements must be exact 0) + pair tables (r5-fixed decode).
  for (int v = tid; v < (48 * SM_STRIDE) / 2; v += 256) {
    ((unsigned int*)Smh)[v] = 0u;
    ((unsigned int*)Sml)[v] = 0u;
  }
  for (int s = tid; s < NSLOT; s += 256) {
    int i = 0, j = 0;
    if (s < 720) {
      int t = s >> 4, m = s & 15;
      int bi = 0, tt = t;
      while (tt >= 9 - bi) { tt -= 9 - bi; ++bi; }
      int bj = bi + 1 + tt;
      i = bi * 4 + (m >> 2);
      j = bj * 4 + (m & 3);
    } else if (s < NPAIR) {
      int idx = s - 720;
      int db = idx / 6;
      int r = idx - db * 6;
      // in-block pairs (0,1),(0,2),(0,3),(1,2),(1,3),(2,3)
      int a = r < 3 ? 0 : (r < 5 ? 1 : 2);
      int bb = r < 3 ? r + 1 : (r < 5 ? r - 1 : 3);
      i = db * 4 + a;
      j = db * 4 + bb;
    }
    pi_t[s] = (unsigned char)i;
    pj_t[s] = (unsigned char)j;
  }

  // ---- P1b: stage x (fp32 padded); per-lane constants; attn_w B-fragments
  // (hi+lo, hoisted once).
  for (int v = tid; v < NF * 16; v += 256) {  // 40 rows x 16 float4
    int f = v >> 4, c4 = v & 15;
    *(float4*)(xs + f * XS_STRIDE + c4 * 4) = *(const float4*)(xg + f * ED + c4 * 4);
  }
  const float ab0 = attn_b[col], ab1 = attn_b[col + 16];
  const float pw0 = proj_w[col], pw1 = proj_w[col + 16];
  const float fcw = fc_w[wid * 16 + col];
  const float fcb = fc_b[0];

  ABFrag fbh[2][2], fbl[2][2];  // [k-step][n-tile]: B[k][n] = attn_w[k][n]
#pragma unroll
  for (int kk = 0; kk < 2; ++kk)
#pragma unroll
    for (int nt = 0; nt < 2; ++nt)
#pragma unroll
      for (int jp = 0; jp < 4; ++jp) {
        int k = kk * 32 + quad * 8 + jp * 2;
        int n = nt * 16 + col;
        split_pack(attn_w[k * AS + n], attn_w[(k + 1) * AS + n],
                   fbh[kk][nt].u[jp], fbl[kk][nt].u[jp]);
      }
  __syncthreads();

  // ---- P2: logits via MFMA. A = bf16-RNE(ip) only (hi); B = w split hi+lo.
  // acc = Ah*Bh + Ah*Bl  (dropped Al*Bh: predicted logit sigma ~3.6e-4).
  for (int t = wid; t < NTILE; t += 4) {
    int s = t * 16 + col;
    int fi = pi_t[s], fj = pj_t[s];
    const float* xi = xs + fi * XS_STRIDE;
    const float* xj = xs + fj * XS_STRIDE;
    ABFrag fah[2];
#pragma unroll
    for (int kk = 0; kk < 2; ++kk) {
      int kb = kk * 32 + quad * 8;
      float4 i0 = *(const float4*)(xi + kb);
      float4 i1 = *(const float4*)(xi + kb + 4);
      float4 j0 = *(const float4*)(xj + kb);
      float4 j1 = *(const float4*)(xj + kb + 4);
      fah[kk].u[0] = pack2(i0.x * j0.x, i0.y * j0.y);
      fah[kk].u[1] = pack2(i0.z * j0.z, i0.w * j0.w);
      fah[kk].u[2] = pack2(i1.x * j1.x, i1.y * j1.y);
      fah[kk].u[3] = pack2(i1.z * j1.z, i1.w * j1.w);
    }
    f32x4 acc0 = {0.f, 0.f, 0.f, 0.f}, acc1 = {0.f, 0.f, 0.f, 0.f};
    acc0 = __builtin_amdgcn_mfma_f32_16x16x32_bf16(fah[0].v, fbh[0][0].v, acc0, 0, 0, 0);
    acc0 = __builtin_amdgcn_mfma_f32_16x16x32_bf16(fah[1].v, fbh[1][0].v, acc0, 0, 0, 0);
    acc0 = __builtin_amdgcn_mfma_f32_16x16x32_bf16(fah[0].v, fbl[0][0].v, acc0, 0, 0, 0);
    acc0 = __builtin_amdgcn_mfma_f32_16x16x32_bf16(fah[1].v, fbl[1][0].v, acc0, 0, 0, 0);
    acc1 = __builtin_amdgcn_mfma_f32_16x16x32_bf16(fah[0].v, fbh[0][1].v, acc1, 0, 0, 0);
    acc1 = __builtin_amdgcn_mfma_f32_16x16x32_bf16(fah[1].v, fbh[1][1].v, acc1, 0, 0, 0);
    acc1 = __builtin_amdgcn_mfma_f32_16x16x32_bf16(fah[0].v, fbl[0][1].v, acc1, 0, 0, 0);
    acc1 = __builtin_amdgcn_mfma_f32_16x16x32_bf16(fah[1].v, fbl[1][1].v, acc1, 0, 0, 0);
    float c0 = fmaxf(acc0[0] + ab0, 0.f) * pw0 + fmaxf(acc1[0] + ab1, 0.f) * pw1;
    float c1 = fmaxf(acc0[1] + ab0, 0.f) * pw0 + fmaxf(acc1[1] + ab1, 0.f) * pw1;
    float c2 = fmaxf(acc0[2] + ab0, 0.f) * pw0 + fmaxf(acc1[2] + ab1, 0.f) * pw1;
    float c3 = fmaxf(acc0[3] + ab0, 0.f) * pw0 + fmaxf(acc1[3] + ab1, 0.f) * pw1;
#pragma unroll
    for (int off = 1; off <= 8; off <<= 1) {
      c0 += __shfl_xor(c0, off);
      c1 += __shfl_xor(c1, off);
      c2 += __shfl_xor(c2, off);
      c3 += __shfl_xor(c3, off);
    }
    if (col == 0) {
      int base = t * 16 + quad * 4;
      float4 st;
      st.x = (base + 0 < NPAIR) ? c0 : -1e30f;
      st.y = (base + 1 < NPAIR) ? c1 : -1e30f;
      st.z = (base + 2 < NPAIR) ? c2 : -1e30f;
      st.w = (base + 3 < NPAIR) ? c3 : -1e30f;
      *(float4*)(logits + base) = st;
    }
  }
  __syncthreads();

  // ---- P3: softmax max, exp fused with UPPER-triangle split-bf16 scatter.
  // [i][j] writes only: j is lane-consecutive for most lanes -> <=2-way, free.
  float lm = -1e30f;
  for (int s2 = tid; s2 < NSLOT; s2 += 256) lm = fmaxf(lm, logits[s2]);
#pragma unroll
  for (int off = 32; off >= 1; off >>= 1) lm = fmaxf(lm, __shfl_xor(lm, off));
  if (lane == 0) red_max[wid] = lm;
  __syncthreads();
  const float mall = fmaxf(fmaxf(red_max[0], red_max[1]),
                           fmaxf(red_max[2], red_max[3]));
  float lsum = 0.f;
  for (int s2 = tid; s2 < NSLOT; s2 += 256) {
    float e = expf(logits[s2] - mall);
    lsum += e;  // pads: exp(-1e30-mall) = 0
    if (s2 < NPAIR) {
      const int i = pi_t[s2], j = pj_t[s2];
      unsigned short eh = bfbits(e);
      unsigned short el = bfbits(e - bf2f(eh));
      Smh[i * SM_STRIDE + j] = eh;
      Sml[i * SM_STRIDE + j] = el;
    }
  }
#pragma unroll
  for (int off = 32; off >= 1; off >>= 1) lsum += __shfl_xor(lsum, off);
  if (lane == 0) red_sum[wid] = lsum;
  __syncthreads();  // covers Sm scatter + red_sum
  const float total = red_sum[0] + red_sum[1] + red_sum[2] + red_sum[3];

  // ---- P4: M = S_up @ X via split MFMA; attn[d] = sum_i x_i[d] * M[i][d]
  // equals sum_{i<j} e_ij x_i[d] x_j[d] directly (no symmetrize, no 0.5).
  // A[m=i][k=j] from Smh/Sml (zero off-upper); B[k=j][n=d] from fp32 xs.
  const int dcol = wid * 16 + col;
  ABFrag fxh[2], fxl[2], fsh[3][2], fsl[3][2];
#pragma unroll
  for (int kt = 0; kt < 2; ++kt) {
    const int kbase = kt * 32 + quad * 8;
    const bool valid = (kt == 0) | (quad == 0);  // k range < 40
    if (valid) {
#pragma unroll
      for (int p = 0; p < 4; ++p) {
        float v0 = xs[(kbase + 2 * p) * XS_STRIDE + dcol];
        float v1 = xs[(kbase + 2 * p + 1) * XS_STRIDE + dcol];
        split_pack(v0, v1, fxh[kt].u[p], fxl[kt].u[p]);
      }
#pragma unroll
      for (int it = 0; it < 3; ++it) {
        fsh[it][kt].q = *(const uint4*)(Smh + (it * 16 + col) * SM_STRIDE + kbase);
        fsl[it][kt].q = *(const uint4*)(Sml + (it * 16 + col) * SM_STRIDE + kbase);
      }
    } else {
      fxh[kt].q = make_uint4(0, 0, 0, 0);
      fxl[kt].q = make_uint4(0, 0, 0, 0);
#pragma unroll
      for (int it = 0; it < 3; ++it) {
        fsh[it][kt].q = make_uint4(0, 0, 0, 0);
        fsl[it][kt].q = make_uint4(0, 0, 0, 0);
      }
    }
  }
  f32x4 mac[3];
#pragma unroll
  for (int it = 0; it < 3; ++it) {
    f32x4 z = {0.f, 0.f, 0.f, 0.f};
    z = __builtin_amdgcn_mfma_f32_16x16x32_bf16(fsh[it][0].v, fxh[0].v, z, 0, 0, 0);
    z = __builtin_amdgcn_mfma_f32_16x16x32_bf16(fsh[it][1].v, fxh[1].v, z, 0, 0, 0);
    z = __builtin_amdgcn_mfma_f32_16x16x32_bf16(fsh[it][0].v, fxl[0].v, z, 0, 0, 0);
    z = __builtin_amdgcn_mfma_f32_16x16x32_bf16(fsh[it][1].v, fxl[1].v, z, 0, 0, 0);
    z = __builtin_amdgcn_mfma_f32_16x16x32_bf16(fsl[it][0].v, fxh[0].v, z, 0, 0, 0);
    z = __builtin_amdgcn_mfma_f32_16x16x32_bf16(fsl[it][1].v, fxh[1].v, z, 0, 0, 0);
    mac[it] = z;
  }
  float part = 0.f;
#pragma unroll
  for (int r = 0; r < 4; ++r)
    part = fmaf(mac[0][r], xs[(quad * 4 + r) * XS_STRIDE + dcol], part);
#pragma unroll
  for (int r = 0; r < 4; ++r)
    part = fmaf(mac[1][r], xs[(16 + quad * 4 + r) * XS_STRIDE + dcol], part);
  if (quad < 2) {
#pragma unroll
    for (int r = 0; r < 4; ++r)
      part = fmaf(mac[2][r], xs[(32 + quad * 4 + r) * XS_STRIDE + dcol], part);
  }
  part += __shfl_xor(part, 16);  // reduce over quads (i groups)
  part += __shfl_xor(part, 32);
  float yp = part * fcw;         // fc_w[dcol]
#pragma unroll
  for (int off = 1; off <= 8; off <<= 1) yp += __shfl_xor(yp, off);  // over d
  if (lane == 0) wsum[wid] = yp;
  __syncthreads();
  if (tid == 0)
    out[b] = (wsum[0] + wsum[1] + wsum[2] + wsum[3]) / total + fcb;
  (void)proj_b;  // cancels in softmax
}

extern "C" void kernel_launch(void* const* d_in, const int* in_sizes, int n_in,
                              void* d_out, int out_size, void* d_ws, size_t ws_size,
                              hipStream_t stream) {
  (void)in_sizes; (void)n_in; (void)out_size; (void)d_ws; (void)ws_size;
  afm_kernel<<<2048, 256, 0, stream>>>(
      (const float*)d_in[0], (const float*)d_in[1], (const float*)d_in[2],
      (const float*)d_in[3], (const float*)d_in[4], (const float*)d_in[5],
      (const float*)d_in[6], (float*)d_out);
}

// Round 9
// 106.725 us; speedup vs baseline: 4.0511x; 1.0751x over previous
//
#include <hip/hip_runtime.h>
#include <hip/hip_bf16.h>

// Round 9: P2 transposed to 32x32x16 MFMA — attn dims on M, pairs on N.
// Kills the per-tile 16-shuffle butterfly (measured ~40% of the dominant
// LDS-pipe cost): reduction over a = 16 in-lane FMAs + one shfl_xor(32).
// Pair cover: 20 rect tiles (4i x 8j, fully above diagonal) + 5 diagonal
// 8-chunk tiles (28 pairs + 4 pads, pj=255). P3 over 800 slots; P4/P5 = r8.

#define NF 40
#define ED 64
#define AS 32
#define NSLOT 800
#define NTILE 25
#define XS_STRIDE 68   // floats; 272B rows, 16B-aligned
#define SM_STRIDE 72   // shorts; 144B rows, 16B-aligned

typedef __attribute__((ext_vector_type(4))) float f32x4;
typedef __attribute__((ext_vector_type(16))) float f32x16;
typedef __attribute__((ext_vector_type(8))) short bf16x8;

union ABFrag { bf16x8 v; unsigned int u[4]; uint4 q; };

__device__ __forceinline__ unsigned short bfbits(float f) {
  union { __hip_bfloat16 h; unsigned short s; } c;
  c.h = __float2bfloat16(f);  // RNE
  return c.s;
}
__device__ __forceinline__ float bf2f(unsigned short s) {
  union { float f; unsigned int u; } c;
  c.u = ((unsigned int)s) << 16;
  return c.f;
}
__device__ __forceinline__ unsigned int pack2(float a, float b) {
  return (unsigned int)bfbits(a) | ((unsigned int)bfbits(b) << 16);
}
// hi = bf16(a),bf16(b); lo = bf16(a-hi_a),bf16(b-hi_b): ~17-bit split
__device__ __forceinline__ void split_pack(float a, float b,
                                           unsigned int& hi, unsigned int& lo) {
  unsigned short ah = bfbits(a), bh = bfbits(b);
  hi = (unsigned int)ah | ((unsigned int)bh << 16);
  lo = (unsigned int)bfbits(a - bf2f(ah)) | ((unsigned int)bfbits(b - bf2f(bh)) << 16);
}

__global__ __launch_bounds__(256) void afm_kernel(
    const float* __restrict__ x, const float* __restrict__ attn_w,
    const float* __restrict__ attn_b, const float* __restrict__ proj_w,
    const float* __restrict__ proj_b, const float* __restrict__ fc_w,
    const float* __restrict__ fc_b, float* __restrict__ out) {
  __shared__ __align__(16) float xs[NF * XS_STRIDE];            // 10880 B
  __shared__ __align__(16) float logits[NSLOT];                 // 3200 B
  __shared__ __align__(16) unsigned short Smh[48 * SM_STRIDE];  // 6912 B
  __shared__ __align__(16) unsigned short Sml[48 * SM_STRIDE];  // 6912 B
  __shared__ float red_max[4], red_sum[4], wsum[4];
  __shared__ unsigned char pi_t[NSLOT], pj_t[NSLOT];

  const int tid = threadIdx.x;
  const int lane = tid & 63;
  const int wid = tid >> 6;
  const int quad = lane >> 4;
  const int col = lane & 15;
  const int half = lane >> 5;       // 32x32 MFMA k-half
  const int m32 = lane & 31;        // 32x32 MFMA row/col index
  const int b = blockIdx.x;
  const float* xg = x + b * (NF * ED);

  // ---- P1a: zero Smh/Sml; build pair tables.
  // Tiles 0..19: 4i x 8j rectangles fully above the diagonal
  //   (j0=1:ib 0-1, j0=2:ib 0-3, j0=3:ib 0-5, j0=4:ib 0-7);
  //   i = ib*4 + (m>>3), j = j0*8 + (m&7).
  // Tiles 20..24: diagonal 8-chunks [8k,8k+8): 28 in-chunk pairs + 4 pads.
  for (int v = tid; v < (48 * SM_STRIDE) / 2; v += 256) {
    ((unsigned int*)Smh)[v] = 0u;
    ((unsigned int*)Sml)[v] = 0u;
  }
  for (int s = tid; s < NSLOT; s += 256) {
    int t = s >> 5, m = s & 31;
    int i = 0, j = 255;  // default: pad
    if (t < 20) {
      int j0, ib;
      if (t < 2) { j0 = 1; ib = t; }
      else if (t < 6) { j0 = 2; ib = t - 2; }
      else if (t < 12) { j0 = 3; ib = t - 6; }
      else { j0 = 4; ib = t - 12; }
      i = ib * 4 + (m >> 3);
      j = j0 * 8 + (m & 7);
    } else if (m < 28) {
      int k = t - 20;
      int mm = m, a = 0;
      while (mm >= 7 - a) { mm -= 7 - a; ++a; }  // triu of 8
      i = 8 * k + a;
      j = 8 * k + a + 1 + mm;
    }
    pi_t[s] = (unsigned char)i;
    pj_t[s] = (unsigned char)j;
  }

  // ---- P1b: stage x; hoist W^T A-frags (hi+lo) + per-lane epilogue consts.
  for (int v = tid; v < NF * 16; v += 256) {  // 40 rows x 16 float4
    int f = v >> 4, c4 = v & 15;
    *(float4*)(xs + f * XS_STRIDE + c4 * 4) = *(const float4*)(xg + f * ED + c4 * 4);
  }
  // A-frag (32x32x16): A[mrow = m32][k = half*8 + e]; A = W^T -> w[d][a=m32].
  ABFrag fwh[4], fwl[4];
#pragma unroll
  for (int s4 = 0; s4 < 4; ++s4)
#pragma unroll
    for (int p = 0; p < 4; ++p) {
      int d = s4 * 16 + half * 8 + 2 * p;
      split_pack(attn_w[d * AS + m32], attn_w[(d + 1) * AS + m32],
                 fwh[s4].u[p], fwl[s4].u[p]);
    }
  // Epilogue constants: C/D row(reg) = (reg&3) + 8*(reg>>2) + 4*half.
  float abv[16], pwv[16];
#pragma unroll
  for (int r = 0; r < 16; ++r) {
    int arow = (r & 3) + 8 * (r >> 2) + 4 * half;
    abv[r] = attn_b[arow];
    pwv[r] = proj_w[arow];
  }
  const float fcw = fc_w[wid * 16 + col];
  const float fcb = fc_b[0];
  __syncthreads();

  // ---- P2: logits via 32x32x16 MFMA, pairs on N. Wave handles t, t+4, ...
  for (int t = wid; t < NTILE; t += 4) {
    const int slot = t * 32 + m32;
    const int fi = pi_t[slot];
    const int fjr = pj_t[slot];
    const bool pad = (fjr == 255);
    const int fj = pad ? 0 : fjr;
    const float* xi = xs + fi * XS_STRIDE + half * 8;
    const float* xj = xs + fj * XS_STRIDE + half * 8;
    f32x16 acc0 = {0,0,0,0,0,0,0,0,0,0,0,0,0,0,0,0};
    f32x16 acc1 = {0,0,0,0,0,0,0,0,0,0,0,0,0,0,0,0};
#pragma unroll
    for (int s4 = 0; s4 < 4; ++s4) {
      float4 i0 = *(const float4*)(xi + s4 * 16);
      float4 i1 = *(const float4*)(xi + s4 * 16 + 4);
      float4 j0 = *(const float4*)(xj + s4 * 16);
      float4 j1 = *(const float4*)(xj + s4 * 16 + 4);
      ABFrag ip;  // B-frag: B[k = half*8+e][n = m32] = ip[pair][d]
      ip.u[0] = pack2(i0.x * j0.x, i0.y * j0.y);
      ip.u[1] = pack2(i0.z * j0.z, i0.w * j0.w);
      ip.u[2] = pack2(i1.x * j1.x, i1.y * j1.y);
      ip.u[3] = pack2(i1.z * j1.z, i1.w * j1.w);
      if (s4 & 1) {  // two chains to halve MFMA latency dependence
        acc1 = __builtin_amdgcn_mfma_f32_32x32x16_bf16(fwh[s4].v, ip.v, acc1, 0, 0, 0);
        acc1 = __builtin_amdgcn_mfma_f32_32x32x16_bf16(fwl[s4].v, ip.v, acc1, 0, 0, 0);
      } else {
        acc0 = __builtin_amdgcn_mfma_f32_32x32x16_bf16(fwh[s4].v, ip.v, acc0, 0, 0, 0);
        acc0 = __builtin_amdgcn_mfma_f32_32x32x16_bf16(fwl[s4].v, ip.v, acc0, 0, 0, 0);
      }
    }
    // Fused relu+proj, in-lane over 16 rows, then one cross-half add.
    float lg = 0.f;
#pragma unroll
    for (int r = 0; r < 16; ++r)
      lg = fmaf(fmaxf(acc0[r] + acc1[r] + abv[r], 0.f), pwv[r], lg);
    lg += __shfl_xor(lg, 32);
    if (lane < 32) logits[t * 32 + lane] = pad ? -1e30f : lg;
  }
  __syncthreads();

  // ---- P3: softmax max, exp fused with upper-triangle split-bf16 scatter.
  float lm = -1e30f;
  for (int s2 = tid; s2 < NSLOT; s2 += 256) lm = fmaxf(lm, logits[s2]);
#pragma unroll
  for (int off = 32; off >= 1; off >>= 1) lm = fmaxf(lm, __shfl_xor(lm, off));
  if (lane == 0) red_max[wid] = lm;
  __syncthreads();
  const float mall = fmaxf(fmaxf(red_max[0], red_max[1]),
                           fmaxf(red_max[2], red_max[3]));
  float lsum = 0.f;
  for (int s2 = tid; s2 < NSLOT; s2 += 256) {
    const int j = pj_t[s2];
    float e = expf(logits[s2] - mall);
    lsum += e;  // pads: exp(-1e30-mall) = 0
    if (j != 255) {
      const int i = pi_t[s2];
      unsigned short eh = bfbits(e);
      unsigned short el = bfbits(e - bf2f(eh));
      Smh[i * SM_STRIDE + j] = eh;
      Sml[i * SM_STRIDE + j] = el;
    }
  }
#pragma unroll
  for (int off = 32; off >= 1; off >>= 1) lsum += __shfl_xor(lsum, off);
  if (lane == 0) red_sum[wid] = lsum;
  __syncthreads();  // covers Sm scatter + red_sum
  const float total = red_sum[0] + red_sum[1] + red_sum[2] + red_sum[3];

  // ---- P4: M = S_up @ X via split 16x16x32 MFMA;
  // attn[d] = sum_i x_i[d]*M[i][d] = sum_{i<j} e_ij x_i[d] x_j[d]. [r8 code]
  const int dcol = wid * 16 + col;
  ABFrag fxh[2], fxl[2], fsh[3][2], fsl[3][2];
#pragma unroll
  for (int kt = 0; kt < 2; ++kt) {
    const int kbase = kt * 32 + quad * 8;
    const bool valid = (kt == 0) | (quad == 0);  // k range < 40
    if (valid) {
#pragma unroll
      for (int p = 0; p < 4; ++p) {
        float v0 = xs[(kbase + 2 * p) * XS_STRIDE + dcol];
        float v1 = xs[(kbase + 2 * p + 1) * XS_STRIDE + dcol];
        split_pack(v0, v1, fxh[kt].u[p], fxl[kt].u[p]);
      }
#pragma unroll
      for (int it = 0; it < 3; ++it) {
        fsh[it][kt].q = *(const uint4*)(Smh + (it * 16 + col) * SM_STRIDE + kbase);
        fsl[it][kt].q = *(const uint4*)(Sml + (it * 16 + col) * SM_STRIDE + kbase);
      }
    } else {
      fxh[kt].q = make_uint4(0, 0, 0, 0);
      fxl[kt].q = make_uint4(0, 0, 0, 0);
#pragma unroll
      for (int it = 0; it < 3; ++it) {
        fsh[it][kt].q = make_uint4(0, 0, 0, 0);
        fsl[it][kt].q = make_uint4(0, 0, 0, 0);
      }
    }
  }
  f32x4 mac[3];
#pragma unroll
  for (int it = 0; it < 3; ++it) {
    f32x4 z = {0.f, 0.f, 0.f, 0.f};
    z = __builtin_amdgcn_mfma_f32_16x16x32_bf16(fsh[it][0].v, fxh[0].v, z, 0, 0, 0);
    z = __builtin_amdgcn_mfma_f32_16x16x32_bf16(fsh[it][1].v, fxh[1].v, z, 0, 0, 0);
    z = __builtin_amdgcn_mfma_f32_16x16x32_bf16(fsh[it][0].v, fxl[0].v, z, 0, 0, 0);
    z = __builtin_amdgcn_mfma_f32_16x16x32_bf16(fsh[it][1].v, fxl[1].v, z, 0, 0, 0);
    z = __builtin_amdgcn_mfma_f32_16x16x32_bf16(fsl[it][0].v, fxh[0].v, z, 0, 0, 0);
    z = __builtin_amdgcn_mfma_f32_16x16x32_bf16(fsl[it][1].v, fxh[1].v, z, 0, 0, 0);
    mac[it] = z;
  }
  float part = 0.f;
#pragma unroll
  for (int r = 0; r < 4; ++r)
    part = fmaf(mac[0][r], xs[(quad * 4 + r) * XS_STRIDE + dcol], part);
#pragma unroll
  for (int r = 0; r < 4; ++r)
    part = fmaf(mac[1][r], xs[(16 + quad * 4 + r) * XS_STRIDE + dcol], part);
  if (quad < 2) {
#pragma unroll
    for (int r = 0; r < 4; ++r)
      part = fmaf(mac[2][r], xs[(32 + quad * 4 + r) * XS_STRIDE + dcol], part);
  }
  part += __shfl_xor(part, 16);  // reduce over quads (i groups)
  part += __shfl_xor(part, 32);
  float yp = part * fcw;         // fc_w[dcol]
#pragma unroll
  for (int off = 1; off <= 8; off <<= 1) yp += __shfl_xor(yp, off);  // over d
  if (lane == 0) wsum[wid] = yp;
  __syncthreads();
  if (tid == 0)
    out[b] = (wsum[0] + wsum[1] + wsum[2] + wsum[3]) / total + fcb;
  (void)proj_b;  // cancels in softmax
}

extern "C" void kernel_launch(void* const* d_in, const int* in_sizes, int n_in,
                              void* d_out, int out_size, void* d_ws, size_t ws_size,
                              hipStream_t stream) {
  (void)in_sizes; (void)n_in; (void)out_size; (void)d_ws; (void)ws_size;
  afm_kernel<<<2048, 256, 0, stream>>>(
      (const float*)d_in[0], (const float*)d_in[1], (const float*)d_in[2],
      (const float*)d_in[3], (const float*)d_in[4], (const float*)d_in[5],
      (const float*)d_in[6], (float*)d_out);
}